// Round 11
// baseline (277.442 us; speedup 1.0000x reference)
//
#include <hip/hip_runtime.h>
#include <stdint.h>

typedef int v4i  __attribute__((ext_vector_type(4)));
typedef int v16i __attribute__((ext_vector_type(16)));

#define CAPACITY  65536
#define BATCH     2048
#define KBITS     1024
#define NSTEP     16      // K-steps of 64 bytes
#define NBUF      3       // triple-buffered B LDS

// ===========================================================================
// MFMA path: dist(q,k) = sumq + sumk - 2*dot(q,k). sumq is constant per query
// row -> drop it; rank by packed ((sumk - 2*dot + 2048)<<16) | key_idx, exact
// (0 <= biased dist <= 3072 < 2^16), reproduces first-max argmax.
// A (queries) read per-fragment from blocked-transposed global (L2-resident);
// B (keys) staged through triple-buffered LDS via global_load_lds.
// Occupancy design: wave tile 64x64 -> acc[2][2]=64 acc regs, total <=128
// per wave -> 4 waves/SIMD from 4 INDEPENDENT blocks (no lockstep).
// ===========================================================================

// ---- queries: bits -> i8, blocked-transposed qT[k/16][m][16] ----------------
__global__ void prep_qT_kernel(const int* __restrict__ in,
                               uint32_t* __restrict__ outT) {
    const int row = blockIdx.x, t = threadIdx.x;   // t covers bits 4t..4t+3
    int4 v = reinterpret_cast<const int4*>(in)[(size_t)row * 256 + t];
    uint32_t b = (uint32_t)(v.x & 1)        | ((uint32_t)(v.y & 1) << 8) |
                 ((uint32_t)(v.z & 1) << 16) | ((uint32_t)(v.w & 1) << 24);
    outT[(size_t)(t >> 2) * (BATCH * 4) + (size_t)row * 4 + (t & 3)] = b;
}

// ---- keys: bits -> i8 row-major, plus per-row bit count ---------------------
__global__ void prep_i8_kernel(const int* __restrict__ in,
                               unsigned char* __restrict__ out8,
                               int* __restrict__ sums) {
    const int row = blockIdx.x, t = threadIdx.x;
    int4 v = reinterpret_cast<const int4*>(in)[(size_t)row * 256 + t];
    uint32_t b = (uint32_t)(v.x & 1)        | ((uint32_t)(v.y & 1) << 8) |
                 ((uint32_t)(v.z & 1) << 16) | ((uint32_t)(v.w & 1) << 24);
    reinterpret_cast<uint32_t*>(out8)[(size_t)row * 256 + t] = b;
    int s = (v.x & 1) + (v.y & 1) + (v.z & 1) + (v.w & 1);
    for (int off = 32; off; off >>= 1) s += __shfl_xor(s, off, 64);
    __shared__ int ws4[4];
    if ((t & 63) == 0) ws4[t >> 6] = s;
    __syncthreads();
    if (t == 0) sums[row] = ws4[0] + ws4[1] + ws4[2] + ws4[3];
}

__global__ void init_best_kernel(uint32_t* __restrict__ best) {
    best[blockIdx.x * 256 + threadIdx.x] = 0xFFFFFFFFu;
}

// Involutive 16B-chunk swizzle within a [rows][64B] tile (idx = row*4+chunk):
// self-inverse, spreads consecutive rows across bank groups. Only mixes bits
// 0..5, so idx offsets that are multiples of 256 commute with it.
__device__ __forceinline__ int swz(int idx) { return idx ^ ((idx >> 3) & 7); }

// ---- GEMM + fused argmin ---------------------------------------------------
// Block tile 128(M) x 128(N), K-step 64 B, 4 waves as 2x2, each wave 2x2
// tiles of mfma_i32_32x32x32_i8 (64x64 per wave). 4 blocks/CU.
__launch_bounds__(256, 4)
__global__ void gemm_scan_kernel(const uint4* __restrict__ aT4,
                                 const unsigned char* __restrict__ ki8,
                                 const int* __restrict__ sumk,
                                 uint32_t* __restrict__ best) {
    __shared__ uint4 sB[NBUF][512];   // 128 rows x 4 chunks -> 24 KB

    const int t    = threadIdx.x;
    const int lane = t & 63, wid = t >> 6;
    const int wr   = wid >> 1, wc = wid & 1;      // wave grid 2x2
    const int ln   = lane & 31, kh = lane >> 5;   // mfma row, k-half

    // XCD-pinned tile order: xcd = blockIdx&7 owns 64 consecutive ntiles,
    // mtile innermost -> per-XCD L2 set ~= 1 MB B + 2 MB A < 4 MB.
    const int b     = blockIdx.x;
    const int slot  = b >> 3;                      // [0, 1024)
    const int ntile = (b & 7) * 64 + (slot >> 4);  // [0, 512)
    const int mtile = slot & 15;                   // [0, 16)
    const int m0 = mtile * 128, n0 = ntile * 128;

    // B staging sources, pre-swizzled (swz involution; LDS dest linear).
    // 2 passes of 256 threads cover the 512-slot B tile.
    const unsigned char* bSrc[2];
#pragma unroll
    for (int i = 0; i < 2; ++i) {
        int idx = swz(i * 256 + t);
        bSrc[i] = ki8 + (size_t)(n0 + (idx >> 2)) * KBITS + (idx & 3) * 16;
    }
    auto STAGE_B = [&](int buf, int kc) {          // 2 x global_load_lds(16B)
#pragma unroll
        for (int i = 0; i < 2; ++i)
            __builtin_amdgcn_global_load_lds(
                (const __attribute__((address_space(1))) void*)(bSrc[i] + kc),
                (__attribute__((address_space(3))) void*)&sB[buf][i * 256 + wid * 64],
                16, 0, 0);
    };

    // B fragment LDS offsets (K-invariant)
    int offB[2][2];
#pragma unroll
    for (int km = 0; km < 2; ++km)
#pragma unroll
        for (int ct = 0; ct < 2; ++ct)
            offB[km][ct] = swz((wc * 64 + ct * 32 + ln) * 4 + km * 2 + kh);

    const int mbase = m0 + wr * 64 + ln;           // A fragment row base

    v16i acc[2][2];
#pragma unroll
    for (int rt = 0; rt < 2; ++rt)
#pragma unroll
        for (int ct = 0; ct < 2; ++ct)
#pragma unroll
            for (int e = 0; e < 16; ++e) acc[rt][ct][e] = 0;

    // prologue: prime 2 B tiles; wait tile 0 only (tile 1 stays in flight)
    STAGE_B(0, 0);
    STAGE_B(1, 64);
    asm volatile("s_waitcnt vmcnt(2)" ::: "memory");
    __builtin_amdgcn_s_barrier();

    int buf = 0;
    for (int s = 0; s < NSTEP; ++s) {
        // A fragments direct from global (issued FIRST; compiler's wait for
        // them is vmcnt(2), leaving the s+2 staging loads in flight)
        uint4 af[2][2];
#pragma unroll
        for (int km = 0; km < 2; ++km)
#pragma unroll
            for (int rt = 0; rt < 2; ++rt)
                af[km][rt] = aT4[(size_t)(s * 4 + km * 2 + kh) * BATCH
                                 + mbase + rt * 32];

        if (s + 2 < NSTEP) {                       // issue B k(s+2); in flight
            int nb = buf + 2; if (nb >= NBUF) nb -= NBUF;
            STAGE_B(nb, (s + 2) * 64);
        }

        uint4 bf[2][2];
#pragma unroll
        for (int km = 0; km < 2; ++km)
#pragma unroll
            for (int ct = 0; ct < 2; ++ct) bf[km][ct] = sB[buf][offB[km][ct]];

        __builtin_amdgcn_s_setprio(1);
#pragma unroll
        for (int rt = 0; rt < 2; ++rt)
#pragma unroll
            for (int ct = 0; ct < 2; ++ct)
                acc[rt][ct] = __builtin_amdgcn_mfma_i32_32x32x32_i8(
                    *(v4i*)&af[0][rt], *(v4i*)&bf[0][ct], acc[rt][ct], 0, 0, 0);
        __builtin_amdgcn_s_setprio(0);
        __builtin_amdgcn_s_setprio(1);
#pragma unroll
        for (int rt = 0; rt < 2; ++rt)
#pragma unroll
            for (int ct = 0; ct < 2; ++ct)
                acc[rt][ct] = __builtin_amdgcn_mfma_i32_32x32x32_i8(
                    *(v4i*)&af[1][rt], *(v4i*)&bf[1][ct], acc[rt][ct], 0, 0, 0);
        __builtin_amdgcn_s_setprio(0);

        if (s < NSTEP - 1) {
            // counted drain: vmcnt(2) + in-order retirement => stage(s+1)
            // complete; stage(s+2) (2 loads) stays in flight. lgkmcnt(0):
            // our reads of buf done before others restage it next step.
            if (s < NSTEP - 2)
                asm volatile("s_waitcnt vmcnt(2) lgkmcnt(0)" ::: "memory");
            else
                asm volatile("s_waitcnt vmcnt(0) lgkmcnt(0)" ::: "memory");
            __builtin_amdgcn_s_barrier();
        }
        buf = buf + 1 == NBUF ? 0 : buf + 1;
    }

    // ---- epilogue: packed argmin, exact tie-break (verified r6/r7/r10) ----
    int sk[2];
#pragma unroll
    for (int ct = 0; ct < 2; ++ct) sk[ct] = sumk[n0 + wc * 64 + ct * 32 + ln];

#pragma unroll
    for (int rt = 0; rt < 2; ++rt) {
#pragma unroll
        for (int r = 0; r < 16; ++r) {
            // verified C/D map: col = lane&31, row = (r&3)+8*(r>>2)+4*(lane>>5)
            const int qrow = m0 + wr * 64 + rt * 32 + (r & 3) + 8 * (r >> 2) + 4 * kh;
            uint32_t bmin = 0xFFFFFFFFu;
#pragma unroll
            for (int ct = 0; ct < 2; ++ct) {
                uint32_t dist = (uint32_t)(sk[ct] - 2 * acc[rt][ct][r] + 2048);
                uint32_t col  = (uint32_t)(n0 + wc * 64 + ct * 32 + ln);
                bmin = min(bmin, (dist << 16) | col);
            }
#pragma unroll
            for (int off = 1; off < 32; off <<= 1)   // reduce over 32 cols
                bmin = min(bmin, (uint32_t)__shfl_xor((int)bmin, off, 64));
            if (ln == 0) atomicMin(&best[qrow], bmin);
        }
    }
}

// ---- best[q] -> gather values row ------------------------------------------
__global__ void finalize_kernel(const uint32_t* __restrict__ best,
                                const float* __restrict__ values,
                                float* __restrict__ out) {
    const int qy  = blockIdx.x;
    const int idx = (int)(best[qy] & 0xFFFFu);
    const float4* v4 = reinterpret_cast<const float4*>(values) + (size_t)idx * 256;
    float4* o4 = reinterpret_cast<float4*>(out) + (size_t)qy * 256;
    o4[threadIdx.x] = v4[threadIdx.x];
}

// ===========================================================================
// Fallback (round-5 VALU scan, 401 us) if ws_size can't hold i8 keys
// ===========================================================================
#define KCHUNK 256
#define NSPLIT (CAPACITY / KCHUNK)

__device__ __forceinline__ uint32_t pack_word(const int4* __restrict__ p) {
    uint32_t word = 0;
#pragma unroll
    for (int j = 0; j < 8; ++j) {
        int4 v = p[j];
        word |= (uint32_t)(v.x & 1) << (4 * j + 0);
        word |= (uint32_t)(v.y & 1) << (4 * j + 1);
        word |= (uint32_t)(v.z & 1) << (4 * j + 2);
        word |= (uint32_t)(v.w & 1) << (4 * j + 3);
    }
    return word;
}

__global__ void pack_bits_kernel(const int* __restrict__ in,
                                 uint32_t* __restrict__ out, int nwords) {
    int w = blockIdx.x * blockDim.x + threadIdx.x;
    if (w >= nwords) return;
    out[w] = pack_word(reinterpret_cast<const int4*>(in) + (size_t)w * 8);
}

__launch_bounds__(256, 4)
__global__ void scan_kernel(const uint32_t* __restrict__ qpack,
                            const uint32_t* __restrict__ kpack,
                            uint32_t* __restrict__ best) {
    const int t      = threadIdx.x;
    const int lane   = t & 63;
    const int wid    = t >> 6;
    const int ksplit = blockIdx.x & (NSPLIT - 1);
    const int qgb    = blockIdx.x >> 8;
    const int query  = qgb * 256 + wid * 64 + lane;

    uint32_t q[32];
    const uint4* qp4 = reinterpret_cast<const uint4*>(qpack + (size_t)query * 32);
#pragma unroll
    for (int j = 0; j < 8; ++j) {
        uint4 v = qp4[j];
        q[4 * j + 0] = v.x; q[4 * j + 1] = v.y;
        q[4 * j + 2] = v.z; q[4 * j + 3] = v.w;
    }
    uint32_t bst = 0xFFFFFFFFu;
    const int k0 = ksplit * KCHUNK;
#pragma unroll 2
    for (int k = k0; k < k0 + KCHUNK; ++k) {
        const uint4* kw4 = reinterpret_cast<const uint4*>(kpack + (size_t)k * 32);
        uint32_t dist = 0;
#pragma unroll
        for (int j = 0; j < 8; ++j) {
            uint4 kv = kw4[j];
            dist += __popc(kv.x ^ q[4 * j + 0]);
            dist += __popc(kv.y ^ q[4 * j + 1]);
            dist += __popc(kv.z ^ q[4 * j + 2]);
            dist += __popc(kv.w ^ q[4 * j + 3]);
        }
        bst = min(bst, (dist << 16) | (uint32_t)k);
    }
    atomicMin(&best[query], bst);
}

// ===========================================================================
extern "C" void kernel_launch(void* const* d_in, const int* in_sizes, int n_in,
                              void* d_out, int out_size, void* d_ws, size_t ws_size,
                              hipStream_t stream) {
    const int*   query  = (const int*)d_in[0];   // [2048, 1024] int32 0/1
    const int*   keys   = (const int*)d_in[1];   // [65536, 1024] int32 0/1
    const float* values = (const float*)d_in[2]; // [65536, 1024] f32
    float*       out    = (float*)d_out;         // [2048, 1024] f32
    char* ws = (char*)d_ws;

    const size_t need = 2097152ULL + 67108864ULL + 262144ULL + 8192ULL;
    if (ws_size >= need) {
        uint32_t* qT  = (uint32_t*)ws;                           // 2 MB blocked-T
        unsigned char* ki8 = (unsigned char*)(ws + 2097152);     // 64 MB
        int* sumk = (int*)(ws + 2097152 + 67108864);             // 256 KB
        uint32_t* best = (uint32_t*)(ws + 2097152 + 67108864 + 262144);

        init_best_kernel<<<BATCH / 256, 256, 0, stream>>>(best);
        prep_qT_kernel<<<BATCH,    256, 0, stream>>>(query, qT);
        prep_i8_kernel<<<CAPACITY, 256, 0, stream>>>(keys, ki8, sumk);
        gemm_scan_kernel<<<16 * 512, 256, 0, stream>>>(
            reinterpret_cast<const uint4*>(qT), ki8, sumk, best);
        finalize_kernel<<<BATCH, 256, 0, stream>>>(best, values, out);
    } else {
        uint32_t* qpack = (uint32_t*)ws;                         // 256 KB
        uint32_t* kpack = (uint32_t*)(ws + 262144);              // 8 MB
        uint32_t* best  = (uint32_t*)(ws + 262144 + 8388608);    // 8 KB

        init_best_kernel<<<BATCH / 256, 256, 0, stream>>>(best);
        pack_bits_kernel<<<BATCH * 32 / 256, 256, 0, stream>>>(query, qpack, BATCH * 32);
        pack_bits_kernel<<<CAPACITY * 32 / 256, 256, 0, stream>>>(keys, kpack, CAPACITY * 32);
        scan_kernel<<<8 * NSPLIT, 256, 0, stream>>>(qpack, kpack, best);
        finalize_kernel<<<BATCH, 256, 0, stream>>>(best, values, out);
    }
}